// Round 9
// baseline (429.158 us; speedup 1.0000x reference)
//
#include <hip/hip_runtime.h>

// GRU with per-row sequence lengths. B=4096, T=200, I=64, H=128 (hardcoded).
// Output[b] = h after seq_lengths[b] steps from h0=0.
//
// Round-9 structure: 512 blocks x 512 thr (launch_bounds(512,2) -- the ONLY
// empirically spill-safe config; r4/r7/r8 showed any other block/bounds combo
// halves the VGPR budget). 8 REAL rows/block -> with VGPR<=128 the HW packs
// 2 independent blocks/CU = 4 waves/SIMD with DE-PHASED barriers (the r5-r8
// wall was lockstep phase serialization at 1 block/CU).
// Wave owns 16 h-cols (48 gate cols): 18 MFMA/step, bw[18]=72 VGPR resident.
// Phantom M handling (M=16 tile, 8 real rows):
//  - A-tile has only 8 rows; lanes lrow>=8 read row lrow&7 (LDS broadcast,
//    free) -- phantom C rows are garbage and simply ignored.
//  - gates/h-writes/stores guarded kgrp<2 (exec-masked upper half).
// x: NO LDS ring -- loaded per-wave from global (L1/L2-hot, all waves read
// the same 2KB/step), 1-step prefetch in regs; f16-cvt at consume time.
// frozen-h: hreg stops updating at t>=Lq (cndmask) -> output==hreg, no
// separate hnreg, and finished rows freeze in LDS (semantics identical).
// exp2-prescale in weights/biases; raw v_exp2/v_rcp gates. __syncthreads only.

#define I_DIM 64
#define H_DIM 128
#define ROWS 8
#define RS 40    // slab row stride in halves (80 B)
#define LOG2E 1.44269504088896f

typedef _Float16 h8 __attribute__((ext_vector_type(8)));
typedef _Float16 h2 __attribute__((ext_vector_type(2)));
typedef float f4 __attribute__((ext_vector_type(4)));

__device__ __forceinline__ float sig2(float xp) {   // xp pre-scaled by log2e
    return __builtin_amdgcn_rcpf(1.0f + __builtin_amdgcn_exp2f(-xp));
}
__device__ __forceinline__ float tanh2(float ap) {  // ap pre-scaled by 2*log2e
    return 1.0f - 2.0f * __builtin_amdgcn_rcpf(__builtin_amdgcn_exp2f(ap) + 1.0f);
}

__global__ __launch_bounds__(512, 2)
void gru_seq_kernel(const float* __restrict__ input,
                    const int* __restrict__ seq_lengths,
                    const float* __restrict__ W_ih,
                    const float* __restrict__ W_hh,
                    const float* __restrict__ b_ih,
                    const float* __restrict__ b_hh,
                    float* __restrict__ out,
                    int B, int T) {
    // h tile: [parity][slab k/32][row(8)][RS]; only cols 0..31 used per slab
    __shared__ __align__(16) _Float16 h_lds[2][4][ROWS][RS];

    const int tid  = threadIdx.x;
    const int lane = tid & 63;
    const int w    = tid >> 6;       // wave 0..7
    const int base = blockIdx.x * ROWS;

    const int lrow  = lane & 15;     // MFMA A-row / C-col index
    const int kgrp  = lane >> 4;     // 0..3
    const int kgrp8 = kgrp * 8;
    const int kgrp4 = kgrp * 4;
    const int arow  = lrow & 7;      // aliased A-tile row (broadcast for lrow>=8)
    const int c0    = w * 16 + lrow; // owned h column

    // ---- sequence lengths ----
    int Lmax = 0;
    for (int i = 0; i < ROWS; ++i) {
        int gr = base + i;
        int L = (gr < B) ? seq_lengths[gr] : 0;
        Lmax = max(Lmax, L);
    }
    if (Lmax > T) Lmax = T;
    int Lq[4];
#pragma unroll
    for (int q = 0; q < 4; ++q) {
        int r  = kgrp4 + q;          // real row iff kgrp<2 (r in 0..7)
        int gr = base + r;
        Lq[q] = (kgrp < 2 && gr < B) ? seq_lengths[gr] : 0;
    }

    // ---- biases, exp2-prescaled ----
    const float br  = (b_ih[c0] + b_hh[c0]) * LOG2E;
    const float bz  = (b_ih[H_DIM + c0] + b_hh[H_DIM + c0]) * LOG2E;
    const float bnh = b_hh[2 * H_DIM + c0] * (2.f * LOG2E);
    const float bnx = b_ih[2 * H_DIM + c0] * (2.f * LOG2E);

    // ---- resident B-fragments (18 x h8 = 72 VGPR), exp2-prescaled ----
    h8 bw[18];
#pragma unroll
    for (int gate = 0; gate < 3; ++gate) {
        const float gs = (gate == 2) ? (2.f * LOG2E) : LOG2E;
        const int j = gate * H_DIM + c0;
#pragma unroll
        for (int kt = 0; kt < 6; ++kt) {
            const int kb = kt * 32 + kgrp8;
            const float* src = (kt < 4) ? (W_hh + j * H_DIM + kb)
                                        : (W_ih + j * I_DIM + (kb - H_DIM));
            f4 f0 = *(const f4*)(src);
            f4 f1 = *(const f4*)(src + 4);
            h8 v;
            v[0] = (_Float16)(f0[0] * gs); v[1] = (_Float16)(f0[1] * gs);
            v[2] = (_Float16)(f0[2] * gs); v[3] = (_Float16)(f0[3] * gs);
            v[4] = (_Float16)(f1[0] * gs); v[5] = (_Float16)(f1[1] * gs);
            v[6] = (_Float16)(f1[2] * gs); v[7] = (_Float16)(f1[3] * gs);
            bw[gate * 6 + kt] = v;
        }
    }

    // ---- zero h parity-0 tile: 4 slabs x 8 rows x 32 cols = 1024 halves ----
    {
        int idx = tid * 2;           // 512 thr x 2 halves
        int sl = idx >> 8, r = (idx >> 5) & 7, cc = idx & 31;
        *(h2*)&h_lds[0][sl][r][cc] = h2{0, 0};
    }

    // ---- x source: row base + arow (clamped); per-lane 4 x f4 per step ----
    int xr = base + arow;
    if (xr >= B) xr = B - 1;
    const float* xsrc = input + (size_t)xr * T * I_DIM;

    // prefetch x(0)
    f4 xp0 = f4{0.f,0.f,0.f,0.f}, xp1 = xp0, xp2 = xp0, xp3 = xp0;
    if (Lmax > 0) {
        xp0 = *(const f4*)(xsrc + kgrp8);
        xp1 = *(const f4*)(xsrc + kgrp8 + 4);
        xp2 = *(const f4*)(xsrc + 32 + kgrp8);
        xp3 = *(const f4*)(xsrc + 32 + kgrp8 + 4);
    }
    __syncthreads();

    const int hs = c0 >> 5;     // h-write slab
    const int hc = c0 & 31;     // h-write col within slab

    float hreg[4] = {0.f, 0.f, 0.f, 0.f};

#define STEP(P, TC) do {                                                              \
        const int t_ = (TC);                                                          \
        /* build current x frags (xpf dies), do x-MFMAs first */                      \
        h8 xg0, xg1;                                                                  \
        xg0[0]=(_Float16)xp0[0]; xg0[1]=(_Float16)xp0[1];                             \
        xg0[2]=(_Float16)xp0[2]; xg0[3]=(_Float16)xp0[3];                             \
        xg0[4]=(_Float16)xp1[0]; xg0[5]=(_Float16)xp1[1];                             \
        xg0[6]=(_Float16)xp1[2]; xg0[7]=(_Float16)xp1[3];                             \
        xg1[0]=(_Float16)xp2[0]; xg1[1]=(_Float16)xp2[1];                             \
        xg1[2]=(_Float16)xp2[2]; xg1[3]=(_Float16)xp2[3];                             \
        xg1[4]=(_Float16)xp3[0]; xg1[5]=(_Float16)xp3[1];                             \
        xg1[6]=(_Float16)xp3[2]; xg1[7]=(_Float16)xp3[3];                             \
        f4 ar  = f4{br, br, br, br};                                                  \
        f4 az  = f4{bz, bz, bz, bz};                                                  \
        f4 axn = f4{bnx, bnx, bnx, bnx};                                              \
        f4 anh = f4{bnh, bnh, bnh, bnh};                                              \
        __builtin_amdgcn_s_setprio(1);                                                \
        ar  = __builtin_amdgcn_mfma_f32_16x16x32_f16(xg0, bw[4],  ar,  0, 0, 0);      \
        az  = __builtin_amdgcn_mfma_f32_16x16x32_f16(xg0, bw[10], az,  0, 0, 0);      \
        axn = __builtin_amdgcn_mfma_f32_16x16x32_f16(xg0, bw[16], axn, 0, 0, 0);      \
        ar  = __builtin_amdgcn_mfma_f32_16x16x32_f16(xg1, bw[5],  ar,  0, 0, 0);      \
        az  = __builtin_amdgcn_mfma_f32_16x16x32_f16(xg1, bw[11], az,  0, 0, 0);      \
        axn = __builtin_amdgcn_mfma_f32_16x16x32_f16(xg1, bw[17], axn, 0, 0, 0);      \
        __builtin_amdgcn_s_setprio(0);                                                \
        /* prefetch x(t+1) (consumed next step; drains cheaply at barrier) */         \
        if (t_ + 1 < Lmax) {                                                          \
            const float* xs_ = xsrc + (size_t)(t_ + 1) * I_DIM;                       \
            xp0 = *(const f4*)(xs_ + kgrp8);                                          \
            xp1 = *(const f4*)(xs_ + kgrp8 + 4);                                      \
            xp2 = *(const f4*)(xs_ + 32 + kgrp8);                                     \
            xp3 = *(const f4*)(xs_ + 32 + kgrp8 + 4);                                 \
        }                                                                             \
        /* h A-frags (8-row tile, lrow>=8 broadcasts row lrow&7) */                   \
        h8 af0 = *(const h8*)&h_lds[P][0][arow][kgrp8];                               \
        h8 af1 = *(const h8*)&h_lds[P][1][arow][kgrp8];                               \
        h8 af2 = *(const h8*)&h_lds[P][2][arow][kgrp8];                               \
        h8 af3 = *(const h8*)&h_lds[P][3][arow][kgrp8];                               \
        __builtin_amdgcn_s_setprio(1);                                                \
        ar  = __builtin_amdgcn_mfma_f32_16x16x32_f16(af0, bw[0],  ar,  0, 0, 0);      \
        az  = __builtin_amdgcn_mfma_f32_16x16x32_f16(af0, bw[6],  az,  0, 0, 0);      \
        anh = __builtin_amdgcn_mfma_f32_16x16x32_f16(af0, bw[12], anh, 0, 0, 0);      \
        ar  = __builtin_amdgcn_mfma_f32_16x16x32_f16(af1, bw[1],  ar,  0, 0, 0);      \
        az  = __builtin_amdgcn_mfma_f32_16x16x32_f16(af1, bw[7],  az,  0, 0, 0);      \
        anh = __builtin_amdgcn_mfma_f32_16x16x32_f16(af1, bw[13], anh, 0, 0, 0);      \
        ar  = __builtin_amdgcn_mfma_f32_16x16x32_f16(af2, bw[2],  ar,  0, 0, 0);      \
        az  = __builtin_amdgcn_mfma_f32_16x16x32_f16(af2, bw[8],  az,  0, 0, 0);      \
        anh = __builtin_amdgcn_mfma_f32_16x16x32_f16(af2, bw[14], anh, 0, 0, 0);      \
        ar  = __builtin_amdgcn_mfma_f32_16x16x32_f16(af3, bw[3],  ar,  0, 0, 0);      \
        az  = __builtin_amdgcn_mfma_f32_16x16x32_f16(af3, bw[9],  az,  0, 0, 0);      \
        anh = __builtin_amdgcn_mfma_f32_16x16x32_f16(af3, bw[15], anh, 0, 0, 0);      \
        __builtin_amdgcn_s_setprio(0);                                                \
        /* gates + frozen-h update + write: real lanes only (kgrp<2) */               \
        if (kgrp < 2) {                                                               \
            _Pragma("unroll")                                                         \
            for (int q = 0; q < 4; ++q) {                                             \
                float r    = sig2(ar[q]);                                             \
                float z    = sig2(az[q]);                                             \
                float n    = tanh2(axn[q] + r * anh[q]);                              \
                float hnew = n + z * (hreg[q] - n);                                   \
                hreg[q] = (t_ < Lq[q]) ? hnew : hreg[q];  /* freeze at Lq */          \
                h_lds[(P) ^ 1][hs][kgrp4 + q][hc] = (_Float16)hreg[q];                \
            }                                                                         \
        }                                                                             \
        __syncthreads();                                                              \
    } while (0)

    int t = 0;
    for (; t + 1 < Lmax; t += 2) {
        STEP(0, t);
        STEP(1, t + 1);
    }
    if (t < Lmax) STEP(0, t);

#undef STEP

    // ---- store h (== hn via frozen-h) for real rows ----
    if (kgrp < 2) {
#pragma unroll
        for (int q = 0; q < 4; ++q) {
            int gr = base + kgrp4 + q;
            if (gr < B) out[(size_t)gr * H_DIM + c0] = hreg[q];
        }
    }
}

extern "C" void kernel_launch(void* const* d_in, const int* in_sizes, int n_in,
                              void* d_out, int out_size, void* d_ws, size_t ws_size,
                              hipStream_t stream) {
    const float* input = (const float*)d_in[0];
    const int*   seq   = (const int*)d_in[1];
    const float* W_ih  = (const float*)d_in[2];
    const float* W_hh  = (const float*)d_in[3];
    const float* b_ih  = (const float*)d_in[4];
    const float* b_hh  = (const float*)d_in[5];
    float* out = (float*)d_out;

    const int B = in_sizes[1];
    const int T = in_sizes[0] / (B * I_DIM);

    const int grid = (B + ROWS - 1) / ROWS;
    gru_seq_kernel<<<grid, 512, 0, stream>>>(input, seq, W_ih, W_hh, b_ih, b_hh, out, B, T);
}

// Round 10
// 188.875 us; speedup vs baseline: 2.2722x; 2.2722x over previous
//
#include <hip/hip_runtime.h>

// GRU with per-row sequence lengths. B=4096, T=200, I=64, H=128 (hardcoded).
// Output[b] = h after seq_lengths[b] steps from h0=0.
//
// Round-10 = r5 skeleton (the only structure that executes as designed:
// 256 blocks x 512 thr, 16 real rows, 8 waves x 16 cols, bw[18] resident,
// x-part MFMA pipelined 1 step ahead) with the LDS phase slimmed:
//  - NO x LDS ring: x A-frags from per-lane global prefetch regs (4xf4,
//    prefetch distance 2 -> the barrier vmcnt drain hits loads issued ~2
//    steps ago, L1-hot, free). LDS reads drop 6->4 b128/wave/step and all
//    x ds_writes disappear.
//  - exp2-prescale folded into f16 weights+biases -> gates are raw
//    v_exp2/v_rcp (no range-scaling muls).
//  - frozen-h: hreg stops updating at t>=Lq -> output==hreg, no hnreg.
// __syncthreads only (r3 raw-barrier raced). setprio(1) around MFMA.
// VGPR target ~115 (<128); tripwire: WRITE_SIZE must stay ~2MB (no spill).

#define I_DIM 64
#define H_DIM 128
#define RS 40    // slab row stride in halves (80 B): b128 reads land 8 lanes/quad = conflict-free
#define LOG2E 1.44269504088896f

typedef _Float16 h8 __attribute__((ext_vector_type(8)));
typedef float f4 __attribute__((ext_vector_type(4)));

__device__ __forceinline__ float sig2(float xp) {   // xp pre-scaled by log2e
    return __builtin_amdgcn_rcpf(1.0f + __builtin_amdgcn_exp2f(-xp));
}
__device__ __forceinline__ float tanh2(float ap) {  // ap pre-scaled by 2*log2e
    return 1.0f - 2.0f * __builtin_amdgcn_rcpf(__builtin_amdgcn_exp2f(ap) + 1.0f);
}

__global__ __launch_bounds__(512, 2)
void gru_seq_kernel(const float* __restrict__ input,
                    const int* __restrict__ seq_lengths,
                    const float* __restrict__ W_ih,
                    const float* __restrict__ W_hh,
                    const float* __restrict__ b_ih,
                    const float* __restrict__ b_hh,
                    float* __restrict__ out,
                    int B, int T) {
    // h tile: [parity][slab k/32][row][RS]; cols 0..31 of each slab used
    __shared__ __align__(16) _Float16 h_lds[2][4][16][RS];

    const int tid  = threadIdx.x;
    const int lane = tid & 63;
    const int w    = tid >> 6;       // wave 0..7
    const int base = blockIdx.x * 16;

    const int lrow  = lane & 15;     // MFMA A-row / C-col index
    const int kgrp  = lane >> 4;     // 0..3
    const int kgrp8 = kgrp * 8;
    const int kgrp4 = kgrp * 4;
    const int c0    = w * 16 + lrow; // owned h column

    // ---- sequence lengths ----
    int Lmax = 0;
    for (int i = 0; i < 16; ++i) {
        int gr = base + i;
        int L = (gr < B) ? seq_lengths[gr] : 0;
        Lmax = max(Lmax, L);
    }
    if (Lmax > T) Lmax = T;
    int Lq[4];
#pragma unroll
    for (int q = 0; q < 4; ++q) {
        int gr = base + kgrp4 + q;
        Lq[q] = (gr < B) ? seq_lengths[gr] : 0;
    }

    // ---- biases, exp2-prescaled ----
    const float br  = (b_ih[c0] + b_hh[c0]) * LOG2E;
    const float bz  = (b_ih[H_DIM + c0] + b_hh[H_DIM + c0]) * LOG2E;
    const float bnh = b_hh[2 * H_DIM + c0] * (2.f * LOG2E);
    const float bnx = b_ih[2 * H_DIM + c0] * (2.f * LOG2E);

    // ---- resident B-fragments (18 x h8 = 72 VGPR), exp2-prescaled.
    // Wcat[j][k]: k 0..127 = W_hh, 128..191 = W_ih; frag (gate,kt):
    // lane holds Wcat[gate*128+c0][kt*32+kgrp8 .. +7].
    h8 bw[18];
#pragma unroll
    for (int gate = 0; gate < 3; ++gate) {
        const float gs = (gate == 2) ? (2.f * LOG2E) : LOG2E;
        const int j = gate * H_DIM + c0;
#pragma unroll
        for (int kt = 0; kt < 6; ++kt) {
            const int kb = kt * 32 + kgrp8;
            const float* src = (kt < 4) ? (W_hh + j * H_DIM + kb)
                                        : (W_ih + j * I_DIM + (kb - H_DIM));
            f4 f0 = *(const f4*)(src);
            f4 f1 = *(const f4*)(src + 4);
            h8 v;
            v[0] = (_Float16)(f0[0] * gs); v[1] = (_Float16)(f0[1] * gs);
            v[2] = (_Float16)(f0[2] * gs); v[3] = (_Float16)(f0[3] * gs);
            v[4] = (_Float16)(f1[0] * gs); v[5] = (_Float16)(f1[1] * gs);
            v[6] = (_Float16)(f1[2] * gs); v[7] = (_Float16)(f1[3] * gs);
            bw[gate * 6 + kt] = v;
        }
    }

    // ---- zero BOTH h parities (h(0)=0; parity-1 garbage for L=0 rows is
    // row-isolated but zero it anyway): 5120 halves = 640 h8 ----
    {
        h8 z = h8{0, 0, 0, 0, 0, 0, 0, 0};
        h8* p = (h8*)&h_lds[0][0][0][0];
        for (int i = tid; i < 640; i += 512) p[i] = z;
    }

    // ---- x source: row = base + lrow; lane's 16 floats per step ----
    int xr = base + lrow;
    if (xr >= B) xr = B - 1;
    const float* xsrc = input + (size_t)xr * T * I_DIM;

    // x-part accumulators, ping-pong by step parity; xp holds x(t+1) raw
    f4 xar[2], xaz[2], xan[2];
    f4 xp0, xp1, xp2, xp3;
    xar[0] = f4{br, br, br, br};
    xaz[0] = f4{bz, bz, bz, bz};
    xan[0] = f4{bnx, bnx, bnx, bnx};
    if (Lmax > 0) {   // x(0) -> x-partials for step 0
        xp0 = *(const f4*)(xsrc + kgrp8);
        xp1 = *(const f4*)(xsrc + kgrp8 + 4);
        xp2 = *(const f4*)(xsrc + 32 + kgrp8);
        xp3 = *(const f4*)(xsrc + 32 + kgrp8 + 4);
        h8 xg0, xg1;
        xg0[0]=(_Float16)xp0[0]; xg0[1]=(_Float16)xp0[1];
        xg0[2]=(_Float16)xp0[2]; xg0[3]=(_Float16)xp0[3];
        xg0[4]=(_Float16)xp1[0]; xg0[5]=(_Float16)xp1[1];
        xg0[6]=(_Float16)xp1[2]; xg0[7]=(_Float16)xp1[3];
        xg1[0]=(_Float16)xp2[0]; xg1[1]=(_Float16)xp2[1];
        xg1[2]=(_Float16)xp2[2]; xg1[3]=(_Float16)xp2[3];
        xg1[4]=(_Float16)xp3[0]; xg1[5]=(_Float16)xp3[1];
        xg1[6]=(_Float16)xp3[2]; xg1[7]=(_Float16)xp3[3];
        xar[0] = __builtin_amdgcn_mfma_f32_16x16x32_f16(xg0, bw[4],  xar[0], 0, 0, 0);
        xaz[0] = __builtin_amdgcn_mfma_f32_16x16x32_f16(xg0, bw[10], xaz[0], 0, 0, 0);
        xan[0] = __builtin_amdgcn_mfma_f32_16x16x32_f16(xg0, bw[16], xan[0], 0, 0, 0);
        xar[0] = __builtin_amdgcn_mfma_f32_16x16x32_f16(xg1, bw[5],  xar[0], 0, 0, 0);
        xaz[0] = __builtin_amdgcn_mfma_f32_16x16x32_f16(xg1, bw[11], xaz[0], 0, 0, 0);
        xan[0] = __builtin_amdgcn_mfma_f32_16x16x32_f16(xg1, bw[17], xan[0], 0, 0, 0);
    }
    if (Lmax > 1) {   // prefetch x(1)
        xp0 = *(const f4*)(xsrc + I_DIM + kgrp8);
        xp1 = *(const f4*)(xsrc + I_DIM + kgrp8 + 4);
        xp2 = *(const f4*)(xsrc + I_DIM + 32 + kgrp8);
        xp3 = *(const f4*)(xsrc + I_DIM + 32 + kgrp8 + 4);
    }
    __syncthreads();

    const int hs = c0 >> 5;     // h-write slab
    const int hc = c0 & 31;     // h-write col within slab

    float hreg[4] = {0.f, 0.f, 0.f, 0.f};

#define STEP(P, TC) do {                                                              \
        const int t_ = (TC);                                                          \
        /* h A-frags: slab kt, row lrow, halves kgrp8..+7 (conflict-free b128) */     \
        h8 af0 = *(const h8*)&h_lds[P][0][lrow][kgrp8];                               \
        h8 af1 = *(const h8*)&h_lds[P][1][lrow][kgrp8];                               \
        h8 af2 = *(const h8*)&h_lds[P][2][lrow][kgrp8];                               \
        h8 af3 = *(const h8*)&h_lds[P][3][lrow][kgrp8];                               \
        f4 ar  = xar[P];                                                              \
        f4 az  = xaz[P];                                                              \
        f4 axn = xan[P];                                                              \
        f4 anh = f4{bnh, bnh, bnh, bnh};                                              \
        __builtin_amdgcn_s_setprio(1);                                                \
        ar  = __builtin_amdgcn_mfma_f32_16x16x32_f16(af0, bw[0],  ar,  0, 0, 0);      \
        az  = __builtin_amdgcn_mfma_f32_16x16x32_f16(af0, bw[6],  az,  0, 0, 0);      \
        anh = __builtin_amdgcn_mfma_f32_16x16x32_f16(af0, bw[12], anh, 0, 0, 0);      \
        ar  = __builtin_amdgcn_mfma_f32_16x16x32_f16(af1, bw[1],  ar,  0, 0, 0);      \
        az  = __builtin_amdgcn_mfma_f32_16x16x32_f16(af1, bw[7],  az,  0, 0, 0);      \
        anh = __builtin_amdgcn_mfma_f32_16x16x32_f16(af1, bw[13], anh, 0, 0, 0);      \
        ar  = __builtin_amdgcn_mfma_f32_16x16x32_f16(af2, bw[2],  ar,  0, 0, 0);      \
        az  = __builtin_amdgcn_mfma_f32_16x16x32_f16(af2, bw[8],  az,  0, 0, 0);      \
        anh = __builtin_amdgcn_mfma_f32_16x16x32_f16(af2, bw[14], anh, 0, 0, 0);      \
        ar  = __builtin_amdgcn_mfma_f32_16x16x32_f16(af3, bw[3],  ar,  0, 0, 0);      \
        az  = __builtin_amdgcn_mfma_f32_16x16x32_f16(af3, bw[9],  az,  0, 0, 0);      \
        anh = __builtin_amdgcn_mfma_f32_16x16x32_f16(af3, bw[15], anh, 0, 0, 0);      \
        __builtin_amdgcn_s_setprio(0);                                                \
        /* x-part for step t+1 from prefetch regs (independent work) */               \
        if (t_ + 1 < Lmax) {                                                          \
            h8 xg0, xg1;                                                              \
            xg0[0]=(_Float16)xp0[0]; xg0[1]=(_Float16)xp0[1];                         \
            xg0[2]=(_Float16)xp0[2]; xg0[3]=(_Float16)xp0[3];                         \
            xg0[4]=(_Float16)xp1[0]; xg0[5]=(_Float16)xp1[1];                         \
            xg0[6]=(_Float16)xp1[2]; xg0[7]=(_Float16)xp1[3];                         \
            xg1[0]=(_Float16)xp2[0]; xg1[1]=(_Float16)xp2[1];                         \
            xg1[2]=(_Float16)xp2[2]; xg1[3]=(_Float16)xp2[3];                         \
            xg1[4]=(_Float16)xp3[0]; xg1[5]=(_Float16)xp3[1];                         \
            xg1[6]=(_Float16)xp3[2]; xg1[7]=(_Float16)xp3[3];                         \
            f4 a0 = f4{br, br, br, br};                                               \
            f4 a1 = f4{bz, bz, bz, bz};                                               \
            f4 a2 = f4{bnx, bnx, bnx, bnx};                                           \
            __builtin_amdgcn_s_setprio(1);                                            \
            a0 = __builtin_amdgcn_mfma_f32_16x16x32_f16(xg0, bw[4],  a0, 0, 0, 0);    \
            a1 = __builtin_amdgcn_mfma_f32_16x16x32_f16(xg0, bw[10], a1, 0, 0, 0);    \
            a2 = __builtin_amdgcn_mfma_f32_16x16x32_f16(xg0, bw[16], a2, 0, 0, 0);    \
            a0 = __builtin_amdgcn_mfma_f32_16x16x32_f16(xg1, bw[5],  a0, 0, 0, 0);    \
            a1 = __builtin_amdgcn_mfma_f32_16x16x32_f16(xg1, bw[11], a1, 0, 0, 0);    \
            a2 = __builtin_amdgcn_mfma_f32_16x16x32_f16(xg1, bw[17], a2, 0, 0, 0);    \
            __builtin_amdgcn_s_setprio(0);                                            \
            xar[(P) ^ 1] = a0; xaz[(P) ^ 1] = a1; xan[(P) ^ 1] = a2;                  \
        }                                                                             \
        /* prefetch x(t+2): drains 2 barriers later, L1-hot, ~free */                 \
        if (t_ + 2 < Lmax) {                                                          \
            const float* xs_ = xsrc + (size_t)(t_ + 2) * I_DIM;                       \
            xp0 = *(const f4*)(xs_ + kgrp8);                                          \
            xp1 = *(const f4*)(xs_ + kgrp8 + 4);                                      \
            xp2 = *(const f4*)(xs_ + 32 + kgrp8);                                     \
            xp3 = *(const f4*)(xs_ + 32 + kgrp8 + 4);                                 \
        }                                                                             \
        /* gates (col=c0, row=kgrp4+q) + frozen-h + publish */                        \
        _Pragma("unroll")                                                             \
        for (int q = 0; q < 4; ++q) {                                                 \
            float r    = sig2(ar[q]);                                                 \
            float z    = sig2(az[q]);                                                 \
            float n    = tanh2(axn[q] + r * anh[q]);                                  \
            float hnew = n + z * (hreg[q] - n);                                       \
            hreg[q] = (t_ < Lq[q]) ? hnew : hreg[q];                                  \
            h_lds[(P) ^ 1][hs][kgrp4 + q][hc] = (_Float16)hreg[q];                    \
        }                                                                             \
        __syncthreads();                                                              \
    } while (0)

    int t = 0;
    for (; t + 1 < Lmax; t += 2) {
        STEP(0, t);
        STEP(1, t + 1);
    }
    if (t < Lmax) STEP(0, t);

#undef STEP

    // ---- store h (== hn via frozen-h) ----
#pragma unroll
    for (int q = 0; q < 4; ++q) {
        int gr = base + kgrp4 + q;
        if (gr < B) out[(size_t)gr * H_DIM + c0] = hreg[q];
    }
}

extern "C" void kernel_launch(void* const* d_in, const int* in_sizes, int n_in,
                              void* d_out, int out_size, void* d_ws, size_t ws_size,
                              hipStream_t stream) {
    const float* input = (const float*)d_in[0];
    const int*   seq   = (const int*)d_in[1];
    const float* W_ih  = (const float*)d_in[2];
    const float* W_hh  = (const float*)d_in[3];
    const float* b_ih  = (const float*)d_in[4];
    const float* b_hh  = (const float*)d_in[5];
    float* out = (float*)d_out;

    const int B = in_sizes[1];
    const int T = in_sizes[0] / (B * I_DIM);

    const int grid = (B + 15) / 16;
    gru_seq_kernel<<<grid, 512, 0, stream>>>(input, seq, W_ih, W_hh, b_ih, b_hh, out, B, T);
}

// Round 11
// 146.387 us; speedup vs baseline: 2.9317x; 1.2902x over previous
//
#include <hip/hip_runtime.h>

// GRU with per-row sequence lengths. B=4096, T=200, I=64, H=128 (hardcoded).
// Output[b] = h after seq_lengths[b] steps from h0=0.
//
// Round-11 = r5 skeleton (best measured: 159us) + VALU/trans diet:
//  - 256 blocks x 512 thr (8 waves, 2/SIMD), 16 real rows/block, wave owns
//    16 h-cols; 12 h-MFMA + 6 x-MFMA (x-part pipelined 1 step ahead);
//    bw[18] f16 B-frags resident (72 VGPR); x staged in 8-step LDS ring
//    (r10 proved global-x is a VALU regression -- reverted).
//  - exp2-prescale + SIGN-FOLD: r/z weights+biases pre-scaled by -log2e,
//    n by +2*log2e -> sigmoid = rcp(1+exp2(a)), tanh = 1-2*rcp(exp2(a)+1),
//    zero scaling/negation instructions in the gate phase.
//  - parity ping-pong x-accumulators (no acc copies, compile-time indices).
//  - frozen-h: hreg freezes at t>=Lq (cndmask) -> output==hreg, no hnreg.
//  - staggered x staging ((t&7)==blockIdx%7) de-phases HBM bursts.
// __syncthreads only (r3 raw-barrier raced). setprio(1) around h-MFMA.

#define I_DIM 64
#define H_DIM 128
#define CH 8     // x-chunk steps
#define HP 136   // h-tile row stride in halves (128 + 8 pad)
#define XP 72    // x-ring row stride in halves (64 + 8 pad)
#define LOG2E 1.44269504088896f

typedef _Float16 h8 __attribute__((ext_vector_type(8)));
typedef _Float16 h4 __attribute__((ext_vector_type(4)));
typedef float f4 __attribute__((ext_vector_type(4)));

__device__ __forceinline__ float sig2n(float an) {  // an = -log2e * preact
    return __builtin_amdgcn_rcpf(1.0f + __builtin_amdgcn_exp2f(an));
}
__device__ __forceinline__ float tanh2(float ap) {  // ap = 2*log2e * preact
    return 1.0f - 2.0f * __builtin_amdgcn_rcpf(__builtin_amdgcn_exp2f(ap) + 1.0f);
}

__global__ __launch_bounds__(512, 2)
void gru_seq_kernel(const float* __restrict__ input,
                    const int* __restrict__ seq_lengths,
                    const float* __restrict__ W_ih,
                    const float* __restrict__ W_hh,
                    const float* __restrict__ b_ih,
                    const float* __restrict__ b_hh,
                    float* __restrict__ out,
                    int B, int T) {
    __shared__ __align__(16) _Float16 h_lds[2][16][HP];          // double-buffered h
    __shared__ __align__(16) _Float16 x_lds[2][CH][16][XP];      // x ring (2 chunks)

    const int tid  = threadIdx.x;
    const int lane = tid & 63;
    const int w    = tid >> 6;     // wave 0..7
    const int base = blockIdx.x * 16;
    const int boff = blockIdx.x % 7;   // stage-phase stagger (0..6)

    const int lrow  = lane & 15;   // MFMA A-row / C-col index
    const int kgrp  = lane >> 4;   // 0..3
    const int kgrp8 = kgrp * 8;
    const int kgrp4 = kgrp * 4;
    const int c0    = w * 16 + lrow;

    // ---- sequence lengths ----
    int Lq[4];
#pragma unroll
    for (int q = 0; q < 4; ++q) {
        int gr = base + kgrp4 + q;
        Lq[q] = (gr < B) ? seq_lengths[gr] : 0;
    }
    int Lmax = 0;
    for (int i = 0; i < 16; ++i) {
        int gr = base + i;
        int L = (gr < B) ? seq_lengths[gr] : 0;
        Lmax = max(Lmax, L);
    }
    if (Lmax > T) Lmax = T;

    // ---- biases: r/z scaled by -log2e (sign-fold), n by +2*log2e ----
    const float br  = (b_ih[c0] + b_hh[c0]) * (-LOG2E);
    const float bz  = (b_ih[H_DIM + c0] + b_hh[H_DIM + c0]) * (-LOG2E);
    const float bnh = b_hh[2 * H_DIM + c0] * (2.f * LOG2E);
    const float bnx = b_ih[2 * H_DIM + c0] * (2.f * LOG2E);

    // ---- resident B-fragments (18 x h8 = 72 VGPR), prescaled per gate ----
    h8 bw[18];
#pragma unroll
    for (int gate = 0; gate < 3; ++gate) {
        const float gs = (gate == 2) ? (2.f * LOG2E) : (-LOG2E);
        const int j = gate * H_DIM + c0;
#pragma unroll
        for (int kt = 0; kt < 6; ++kt) {
            const int kb = kt * 32 + kgrp8;
            const float* src = (kt < 4) ? (W_hh + j * H_DIM + kb)
                                        : (W_ih + j * I_DIM + (kb - H_DIM));
            f4 f0 = *(const f4*)(src);
            f4 f1 = *(const f4*)(src + 4);
            h8 v;
            v[0] = (_Float16)(f0[0] * gs); v[1] = (_Float16)(f0[1] * gs);
            v[2] = (_Float16)(f0[2] * gs); v[3] = (_Float16)(f0[3] * gs);
            v[4] = (_Float16)(f1[0] * gs); v[5] = (_Float16)(f1[1] * gs);
            v[6] = (_Float16)(f1[2] * gs); v[7] = (_Float16)(f1[3] * gs);
            bw[gate * 6 + kt] = v;
        }
    }

    // ---- zero h buffer 0 (h(0) = 0) ----
    {
        int idx = tid * 4;             // 16*128 = 2048 halves / 512 threads
        int r = idx >> 7, cc = idx & 127;
        *(h4*)&h_lds[0][r][cc] = h4{0, 0, 0, 0};
    }

    // ---- x staging geometry: 32 thr/row; thread covers 4 steps ----
    const int srow = tid >> 5;                    // 0..15
    const int si0  = (tid & 31) >> 4;             // 0..1
    const int icol = (tid & 15) * 4;              // 0,4,..,60
    const int gxr  = base + srow;
    const float* xsrc = input + (size_t)gxr * T * I_DIM;
    const bool xok = (gxr < B);

    // prologue: stage chunk 0 (steps 0..7) into slot 0
    if (Lmax > 0) {
        f4 xv[4];
#pragma unroll
        for (int j = 0; j < 4; ++j) {
            int s = si0 + 2 * j;
            xv[j] = f4{0.f, 0.f, 0.f, 0.f};
            if (xok && s < T) xv[j] = *(const f4*)(xsrc + (size_t)s * I_DIM + icol);
        }
#pragma unroll
        for (int j = 0; j < 4; ++j) {
            int s = si0 + 2 * j;
            h4 hv;
            hv[0] = (_Float16)xv[j][0]; hv[1] = (_Float16)xv[j][1];
            hv[2] = (_Float16)xv[j][2]; hv[3] = (_Float16)xv[j][3];
            *(h4*)&x_lds[0][s][srow][icol] = hv;
        }
    }
    __syncthreads();

    // ---- x-part accumulators, parity ping-pong; set 0 = step 0 ----
    f4 xar[2], xaz[2], xan[2];
    xar[0] = f4{br, br, br, br};
    xaz[0] = f4{bz, bz, bz, bz};
    xan[0] = f4{bnx, bnx, bnx, bnx};
    if (Lmax > 0) {
        h8 xg0 = *(const h8*)&x_lds[0][0][lrow][kgrp8];
        h8 xg1 = *(const h8*)&x_lds[0][0][lrow][32 + kgrp8];
        xar[0] = __builtin_amdgcn_mfma_f32_16x16x32_f16(xg0, bw[4],  xar[0], 0, 0, 0);
        xaz[0] = __builtin_amdgcn_mfma_f32_16x16x32_f16(xg0, bw[10], xaz[0], 0, 0, 0);
        xan[0] = __builtin_amdgcn_mfma_f32_16x16x32_f16(xg0, bw[16], xan[0], 0, 0, 0);
        xar[0] = __builtin_amdgcn_mfma_f32_16x16x32_f16(xg1, bw[5],  xar[0], 0, 0, 0);
        xaz[0] = __builtin_amdgcn_mfma_f32_16x16x32_f16(xg1, bw[11], xaz[0], 0, 0, 0);
        xan[0] = __builtin_amdgcn_mfma_f32_16x16x32_f16(xg1, bw[17], xan[0], 0, 0, 0);
    }

    const int hs = c0;          // h-write col (row-major [row][HP])

    float hreg[4] = {0.f, 0.f, 0.f, 0.f};

#define STEP(P, TC) do {                                                              \
        const int t_ = (TC);                                                          \
        /* stage next-chunk loads at this block's stagger step */                     \
        f4 xv0, xv1, xv2, xv3;                                                        \
        const bool do_stage = ((t_ & 7) == boff) && (((t_ >> 3) + 1) * CH < Lmax);    \
        if (do_stage) {                                                               \
            const int t0 = ((t_ >> 3) + 1) * CH;                                      \
            xv0 = xv1 = xv2 = xv3 = f4{0.f, 0.f, 0.f, 0.f};                           \
            if (xok) {                                                                \
                int s0 = t0 + si0;                                                    \
                if (s0     < T) xv0 = *(const f4*)(xsrc + (size_t)(s0    ) * I_DIM + icol); \
                if (s0 + 2 < T) xv1 = *(const f4*)(xsrc + (size_t)(s0 + 2) * I_DIM + icol); \
                if (s0 + 4 < T) xv2 = *(const f4*)(xsrc + (size_t)(s0 + 4) * I_DIM + icol); \
                if (s0 + 6 < T) xv3 = *(const f4*)(xsrc + (size_t)(s0 + 6) * I_DIM + icol); \
            }                                                                         \
        }                                                                             \
        /* h A-frags */                                                               \
        h8 af0 = *(const h8*)&h_lds[P][lrow][0 * 32 + kgrp8];                         \
        h8 af1 = *(const h8*)&h_lds[P][lrow][1 * 32 + kgrp8];                         \
        h8 af2 = *(const h8*)&h_lds[P][lrow][2 * 32 + kgrp8];                         \
        h8 af3 = *(const h8*)&h_lds[P][lrow][3 * 32 + kgrp8];                         \
        /* x A-frags for step t+1 */                                                  \
        const int sl_ = ((t_ + 1) >> 3) & 1, ss_ = (t_ + 1) & 7;                      \
        h8 xg0 = *(const h8*)&x_lds[sl_][ss_][lrow][kgrp8];                           \
        h8 xg1 = *(const h8*)&x_lds[sl_][ss_][lrow][32 + kgrp8];                      \
        f4 ar  = xar[P];                                                              \
        f4 az  = xaz[P];                                                              \
        f4 axn = xan[P];                                                              \
        f4 anh = f4{bnh, bnh, bnh, bnh};                                              \
        __builtin_amdgcn_s_setprio(1);                                                \
        ar  = __builtin_amdgcn_mfma_f32_16x16x32_f16(af0, bw[0],  ar,  0, 0, 0);      \
        az  = __builtin_amdgcn_mfma_f32_16x16x32_f16(af0, bw[6],  az,  0, 0, 0);      \
        anh = __builtin_amdgcn_mfma_f32_16x16x32_f16(af0, bw[12], anh, 0, 0, 0);      \
        ar  = __builtin_amdgcn_mfma_f32_16x16x32_f16(af1, bw[1],  ar,  0, 0, 0);      \
        az  = __builtin_amdgcn_mfma_f32_16x16x32_f16(af1, bw[7],  az,  0, 0, 0);      \
        anh = __builtin_amdgcn_mfma_f32_16x16x32_f16(af1, bw[13], anh, 0, 0, 0);      \
        ar  = __builtin_amdgcn_mfma_f32_16x16x32_f16(af2, bw[2],  ar,  0, 0, 0);      \
        az  = __builtin_amdgcn_mfma_f32_16x16x32_f16(af2, bw[8],  az,  0, 0, 0);      \
        anh = __builtin_amdgcn_mfma_f32_16x16x32_f16(af2, bw[14], anh, 0, 0, 0);      \
        ar  = __builtin_amdgcn_mfma_f32_16x16x32_f16(af3, bw[3],  ar,  0, 0, 0);      \
        az  = __builtin_amdgcn_mfma_f32_16x16x32_f16(af3, bw[9],  az,  0, 0, 0);      \
        anh = __builtin_amdgcn_mfma_f32_16x16x32_f16(af3, bw[15], anh, 0, 0, 0);      \
        /* x-part for step t+1 (independent) */                                       \
        if (t_ + 1 < Lmax) {                                                          \
            f4 a0 = f4{br, br, br, br};                                               \
            f4 a1 = f4{bz, bz, bz, bz};                                               \
            f4 a2 = f4{bnx, bnx, bnx, bnx};                                           \
            a0 = __builtin_amdgcn_mfma_f32_16x16x32_f16(xg0, bw[4],  a0, 0, 0, 0);    \
            a1 = __builtin_amdgcn_mfma_f32_16x16x32_f16(xg0, bw[10], a1, 0, 0, 0);    \
            a2 = __builtin_amdgcn_mfma_f32_16x16x32_f16(xg0, bw[16], a2, 0, 0, 0);    \
            a0 = __builtin_amdgcn_mfma_f32_16x16x32_f16(xg1, bw[5],  a0, 0, 0, 0);    \
            a1 = __builtin_amdgcn_mfma_f32_16x16x32_f16(xg1, bw[11], a1, 0, 0, 0);    \
            a2 = __builtin_amdgcn_mfma_f32_16x16x32_f16(xg1, bw[17], a2, 0, 0, 0);    \
            xar[(P) ^ 1] = a0; xaz[(P) ^ 1] = a1; xan[(P) ^ 1] = a2;                  \
        }                                                                             \
        __builtin_amdgcn_s_setprio(0);                                                \
        /* gates: sigmoid = rcp(1+exp2(a)) [a pre-negated], tanh via exp2 */          \
        _Pragma("unroll")                                                             \
        for (int q = 0; q < 4; ++q) {                                                 \
            float r    = sig2n(ar[q]);                                                \
            float z    = sig2n(az[q]);                                                \
            float n    = tanh2(axn[q] + r * anh[q]);                                  \
            float hnew = n + z * (hreg[q] - n);                                       \
            hreg[q] = (t_ < Lq[q]) ? hnew : hreg[q];  /* frozen-h */                  \
            h_lds[(P) ^ 1][kgrp4 + q][hs] = (_Float16)hreg[q];                        \
        }                                                                             \
        /* write staged x-chunk */                                                    \
        if (do_stage) {                                                               \
            const int ws_ = ((t_ >> 3) + 1) & 1;                                      \
            h4 hv;                                                                    \
            hv[0] = (_Float16)xv0[0]; hv[1] = (_Float16)xv0[1];                       \
            hv[2] = (_Float16)xv0[2]; hv[3] = (_Float16)xv0[3];                       \
            *(h4*)&x_lds[ws_][si0][srow][icol] = hv;                                  \
            hv[0] = (_Float16)xv1[0]; hv[1] = (_Float16)xv1[1];                       \
            hv[2] = (_Float16)xv1[2]; hv[3] = (_Float16)xv1[3];                       \
            *(h4*)&x_lds[ws_][si0 + 2][srow][icol] = hv;                              \
            hv[0] = (_Float16)xv2[0]; hv[1] = (_Float16)xv2[1];                       \
            hv[2] = (_Float16)xv2[2]; hv[3] = (_Float16)xv2[3];                       \
            *(h4*)&x_lds[ws_][si0 + 4][srow][icol] = hv;                              \
            hv[0] = (_Float16)xv3[0]; hv[1] = (_Float16)xv3[1];                       \
            hv[2] = (_Float16)xv3[2]; hv[3] = (_Float16)xv3[3];                       \
            *(h4*)&x_lds[ws_][si0 + 6][srow][icol] = hv;                              \
        }                                                                             \
        __syncthreads();                                                              \
    } while (0)

    int t = 0;
    for (; t + 1 < Lmax; t += 2) {
        STEP(0, t);
        STEP(1, t + 1);
    }
    if (t < Lmax) STEP(0, t);

#undef STEP

    // ---- store h (== hn via frozen-h) ----
#pragma unroll
    for (int q = 0; q < 4; ++q) {
        int gr = base + kgrp4 + q;
        if (gr < B) out[(size_t)gr * H_DIM + c0] = hreg[q];
    }
}

extern "C" void kernel_launch(void* const* d_in, const int* in_sizes, int n_in,
                              void* d_out, int out_size, void* d_ws, size_t ws_size,
                              hipStream_t stream) {
    const float* input = (const float*)d_in[0];
    const int*   seq   = (const int*)d_in[1];
    const float* W_ih  = (const float*)d_in[2];
    const float* W_hh  = (const float*)d_in[3];
    const float* b_ih  = (const float*)d_in[4];
    const float* b_hh  = (const float*)d_in[5];
    float* out = (float*)d_out;

    const int B = in_sizes[1];
    const int T = in_sizes[0] / (B * I_DIM);

    const int grid = (B + 15) / 16;
    gru_seq_kernel<<<grid, 512, 0, stream>>>(input, seq, W_ih, W_hh, b_ih, b_hh, out, B, T);
}

// Round 12
// 143.344 us; speedup vs baseline: 2.9939x; 1.0212x over previous
//
#include <hip/hip_runtime.h>

// GRU with per-row sequence lengths. B=4096, T=200, I=64, H=128 (hardcoded).
// Output[b] = h after seq_lengths[b] steps from h0=0.
//
// Round-12 = r11 (146us) + C^T operand swap:
// compute gates^T = Wcat . [h|x]^T instead of [h|x] . Wcat^T.
//  - A-frag = weight fragments: IDENTICAL registers to r11's B-frags.
//  - B-frag = h/x rows from LDS: IDENTICAL read addresses to r11's A-frags.
//  - C flips: lane owns ONE batch row (n=lane&15) x 4 CONSECUTIVE h-cols
//    (m=kgrp*4+q). So the h-write is one ds_write_b64 (was 4 scattered
//    ds_write_b16), seq-length check is a per-lane scalar, and the final
//    store is one global_store_dwordx4.
//  - biases become per-lane f4 vectors (+12 VGPR, loaded once).
// Everything else from r11: 256 blocks x 512 thr, 16 rows, 8 waves x 16
// cols, x LDS ring w/ stagger, exp2-prescale + sign-fold, parity ping-pong
// x-accumulators, frozen-h, __syncthreads, setprio around MFMA.

#define I_DIM 64
#define H_DIM 128
#define CH 8     // x-chunk steps
#define HP 136   // h-tile row stride in halves (128 + 8 pad)
#define XP 72    // x-ring row stride in halves (64 + 8 pad)
#define LOG2E 1.44269504088896f

typedef _Float16 h8 __attribute__((ext_vector_type(8)));
typedef _Float16 h4 __attribute__((ext_vector_type(4)));
typedef float f4 __attribute__((ext_vector_type(4)));

__device__ __forceinline__ float sig2n(float an) {  // an = -log2e * preact
    return __builtin_amdgcn_rcpf(1.0f + __builtin_amdgcn_exp2f(an));
}
__device__ __forceinline__ float tanh2(float ap) {  // ap = 2*log2e * preact
    return 1.0f - 2.0f * __builtin_amdgcn_rcpf(__builtin_amdgcn_exp2f(ap) + 1.0f);
}

__global__ __launch_bounds__(512, 2)
void gru_seq_kernel(const float* __restrict__ input,
                    const int* __restrict__ seq_lengths,
                    const float* __restrict__ W_ih,
                    const float* __restrict__ W_hh,
                    const float* __restrict__ b_ih,
                    const float* __restrict__ b_hh,
                    float* __restrict__ out,
                    int B, int T) {
    __shared__ __align__(16) _Float16 h_lds[2][16][HP];          // double-buffered h
    __shared__ __align__(16) _Float16 x_lds[2][CH][16][XP];      // x ring (2 chunks)

    const int tid  = threadIdx.x;
    const int lane = tid & 63;
    const int w    = tid >> 6;     // wave 0..7
    const int base = blockIdx.x * 16;
    const int boff = blockIdx.x % 7;   // stage-phase stagger (0..6)

    const int lrow  = lane & 15;   // now: batch row owned by this lane (C col)
    const int kgrp  = lane >> 4;   // 0..3
    const int kgrp8 = kgrp * 8;
    const int kgrp4 = kgrp * 4;
    const int cb    = w * 16 + kgrp4;   // first of this lane's 4 h-cols

    // ---- sequence lengths ----
    const int gb = base + lrow;
    const int L = (gb < B) ? seq_lengths[gb] : 0;   // per-lane scalar
    int Lmax = 0;
    for (int i = 0; i < 16; ++i) {
        int gr = base + i;
        int Li = (gr < B) ? seq_lengths[gr] : 0;
        Lmax = max(Lmax, Li);
    }
    if (Lmax > T) Lmax = T;

    // ---- bias vectors (element q -> h-col cb+q), prescaled + sign-folded ----
    const f4 brv  = (*(const f4*)(b_ih + cb) + *(const f4*)(b_hh + cb)) * (-LOG2E);
    const f4 bzv  = (*(const f4*)(b_ih + H_DIM + cb) + *(const f4*)(b_hh + H_DIM + cb)) * (-LOG2E);
    const f4 bnxv = (*(const f4*)(b_ih + 2 * H_DIM + cb)) * (2.f * LOG2E);
    const f4 bnhv = (*(const f4*)(b_hh + 2 * H_DIM + cb)) * (2.f * LOG2E);

    // ---- resident weight A-fragments (18 x h8 = 72 VGPR), prescaled.
    // A[m][k]: lane holds Wcat[gate*128 + w*16 + lrow][kt*32 + kgrp8 ..+7].
    // (identical registers to r11's B-frags; role is now A.)
    h8 aw[18];
    {
        const int jrow = w * 16 + lrow;
#pragma unroll
        for (int gate = 0; gate < 3; ++gate) {
            const float gs = (gate == 2) ? (2.f * LOG2E) : (-LOG2E);
            const int j = gate * H_DIM + jrow;
#pragma unroll
            for (int kt = 0; kt < 6; ++kt) {
                const int kb = kt * 32 + kgrp8;
                const float* src = (kt < 4) ? (W_hh + j * H_DIM + kb)
                                            : (W_ih + j * I_DIM + (kb - H_DIM));
                f4 f0 = *(const f4*)(src);
                f4 f1 = *(const f4*)(src + 4);
                h8 v;
                v[0] = (_Float16)(f0[0] * gs); v[1] = (_Float16)(f0[1] * gs);
                v[2] = (_Float16)(f0[2] * gs); v[3] = (_Float16)(f0[3] * gs);
                v[4] = (_Float16)(f1[0] * gs); v[5] = (_Float16)(f1[1] * gs);
                v[6] = (_Float16)(f1[2] * gs); v[7] = (_Float16)(f1[3] * gs);
                aw[gate * 6 + kt] = v;
            }
        }
    }

    // ---- zero h buffer 0 (h(0) = 0) ----
    {
        int idx = tid * 4;             // 16*128 = 2048 halves / 512 threads
        int r = idx >> 7, cc = idx & 127;
        *(h4*)&h_lds[0][r][cc] = h4{0, 0, 0, 0};
    }

    // ---- x staging geometry: 32 thr/row; thread covers 4 steps ----
    const int srow = tid >> 5;                    // 0..15
    const int si0  = (tid & 31) >> 4;             // 0..1
    const int icol = (tid & 15) * 4;              // 0,4,..,60
    const int gxr  = base + srow;
    const float* xsrc = input + (size_t)gxr * T * I_DIM;
    const bool xok = (gxr < B);

    // prologue: stage chunk 0 (steps 0..7) into slot 0
    if (Lmax > 0) {
        f4 xv[4];
#pragma unroll
        for (int j = 0; j < 4; ++j) {
            int s = si0 + 2 * j;
            xv[j] = f4{0.f, 0.f, 0.f, 0.f};
            if (xok && s < T) xv[j] = *(const f4*)(xsrc + (size_t)s * I_DIM + icol);
        }
#pragma unroll
        for (int j = 0; j < 4; ++j) {
            int s = si0 + 2 * j;
            h4 hv;
            hv[0] = (_Float16)xv[j][0]; hv[1] = (_Float16)xv[j][1];
            hv[2] = (_Float16)xv[j][2]; hv[3] = (_Float16)xv[j][3];
            *(h4*)&x_lds[0][s][srow][icol] = hv;
        }
    }
    __syncthreads();

    // ---- x-part accumulators (gates^T layout), parity ping-pong ----
    f4 xar[2], xaz[2], xan[2];
    xar[0] = brv;
    xaz[0] = bzv;
    xan[0] = bnxv;
    if (Lmax > 0) {
        h8 xg0 = *(const h8*)&x_lds[0][0][lrow][kgrp8];
        h8 xg1 = *(const h8*)&x_lds[0][0][lrow][32 + kgrp8];
        xar[0] = __builtin_amdgcn_mfma_f32_16x16x32_f16(aw[4],  xg0, xar[0], 0, 0, 0);
        xaz[0] = __builtin_amdgcn_mfma_f32_16x16x32_f16(aw[10], xg0, xaz[0], 0, 0, 0);
        xan[0] = __builtin_amdgcn_mfma_f32_16x16x32_f16(aw[16], xg0, xan[0], 0, 0, 0);
        xar[0] = __builtin_amdgcn_mfma_f32_16x16x32_f16(aw[5],  xg1, xar[0], 0, 0, 0);
        xaz[0] = __builtin_amdgcn_mfma_f32_16x16x32_f16(aw[11], xg1, xaz[0], 0, 0, 0);
        xan[0] = __builtin_amdgcn_mfma_f32_16x16x32_f16(aw[17], xg1, xan[0], 0, 0, 0);
    }

    float hreg[4] = {0.f, 0.f, 0.f, 0.f};

#define STEP(P, TC) do {                                                              \
        const int t_ = (TC);                                                          \
        /* stage next-chunk loads at this block's stagger step */                     \
        f4 xv0, xv1, xv2, xv3;                                                        \
        const bool do_stage = ((t_ & 7) == boff) && (((t_ >> 3) + 1) * CH < Lmax);    \
        if (do_stage) {                                                               \
            const int t0 = ((t_ >> 3) + 1) * CH;                                      \
            xv0 = xv1 = xv2 = xv3 = f4{0.f, 0.f, 0.f, 0.f};                           \
            if (xok) {                                                                \
                int s0 = t0 + si0;                                                    \
                if (s0     < T) xv0 = *(const f4*)(xsrc + (size_t)(s0    ) * I_DIM + icol); \
                if (s0 + 2 < T) xv1 = *(const f4*)(xsrc + (size_t)(s0 + 2) * I_DIM + icol); \
                if (s0 + 4 < T) xv2 = *(const f4*)(xsrc + (size_t)(s0 + 4) * I_DIM + icol); \
                if (s0 + 6 < T) xv3 = *(const f4*)(xsrc + (size_t)(s0 + 6) * I_DIM + icol); \
            }                                                                         \
        }                                                                             \
        /* h B-frags: B[k][n]=h[n=lrow][k] (same addresses as r11) */                 \
        h8 hb0 = *(const h8*)&h_lds[P][lrow][0 * 32 + kgrp8];                         \
        h8 hb1 = *(const h8*)&h_lds[P][lrow][1 * 32 + kgrp8];                         \
        h8 hb2 = *(const h8*)&h_lds[P][lrow][2 * 32 + kgrp8];                         \
        h8 hb3 = *(const h8*)&h_lds[P][lrow][3 * 32 + kgrp8];                         \
        /* x B-frags for step t+1 */                                                  \
        const int sl_ = ((t_ + 1) >> 3) & 1, ss_ = (t_ + 1) & 7;                      \
        h8 xg0 = *(const h8*)&x_lds[sl_][ss_][lrow][kgrp8];                           \
        h8 xg1 = *(const h8*)&x_lds[sl_][ss_][lrow][32 + kgrp8];                      \
        f4 ar  = xar[P];                                                              \
        f4 az  = xaz[P];                                                              \
        f4 axn = xan[P];                                                              \
        f4 anh = bnhv;                                                                \
        __builtin_amdgcn_s_setprio(1);                                                \
        ar  = __builtin_amdgcn_mfma_f32_16x16x32_f16(aw[0],  hb0, ar,  0, 0, 0);      \
        az  = __builtin_amdgcn_mfma_f32_16x16x32_f16(aw[6],  hb0, az,  0, 0, 0);      \
        anh = __builtin_amdgcn_mfma_f32_16x16x32_f16(aw[12], hb0, anh, 0, 0, 0);      \
        ar  = __builtin_amdgcn_mfma_f32_16x16x32_f16(aw[1],  hb1, ar,  0, 0, 0);      \
        az  = __builtin_amdgcn_mfma_f32_16x16x32_f16(aw[7],  hb1, az,  0, 0, 0);      \
        anh = __builtin_amdgcn_mfma_f32_16x16x32_f16(aw[13], hb1, anh, 0, 0, 0);      \
        ar  = __builtin_amdgcn_mfma_f32_16x16x32_f16(aw[2],  hb2, ar,  0, 0, 0);      \
        az  = __builtin_amdgcn_mfma_f32_16x16x32_f16(aw[8],  hb2, az,  0, 0, 0);      \
        anh = __builtin_amdgcn_mfma_f32_16x16x32_f16(aw[14], hb2, anh, 0, 0, 0);      \
        ar  = __builtin_amdgcn_mfma_f32_16x16x32_f16(aw[3],  hb3, ar,  0, 0, 0);      \
        az  = __builtin_amdgcn_mfma_f32_16x16x32_f16(aw[9],  hb3, az,  0, 0, 0);      \
        anh = __builtin_amdgcn_mfma_f32_16x16x32_f16(aw[15], hb3, anh, 0, 0, 0);      \
        /* x-part for step t+1 (independent) */                                       \
        if (t_ + 1 < Lmax) {                                                          \
            f4 a0 = brv;                                                              \
            f4 a1 = bzv;                                                              \
            f4 a2 = bnxv;                                                             \
            a0 = __builtin_amdgcn_mfma_f32_16x16x32_f16(aw[4],  xg0, a0, 0, 0, 0);    \
            a1 = __builtin_amdgcn_mfma_f32_16x16x32_f16(aw[10], xg0, a1, 0, 0, 0);    \
            a2 = __builtin_amdgcn_mfma_f32_16x16x32_f16(aw[16], xg0, a2, 0, 0, 0);    \
            a0 = __builtin_amdgcn_mfma_f32_16x16x32_f16(aw[5],  xg1, a0, 0, 0, 0);    \
            a1 = __builtin_amdgcn_mfma_f32_16x16x32_f16(aw[11], xg1, a1, 0, 0, 0);    \
            a2 = __builtin_amdgcn_mfma_f32_16x16x32_f16(aw[17], xg1, a2, 0, 0, 0);    \
            xar[(P) ^ 1] = a0; xaz[(P) ^ 1] = a1; xan[(P) ^ 1] = a2;                  \
        }                                                                             \
        __builtin_amdgcn_s_setprio(0);                                                \
        /* gates: lane = batch row lrow, cols cb..cb+3; frozen-h at L */              \
        const bool upd_ = (t_ < L);                                                   \
        _Pragma("unroll")                                                             \
        for (int q = 0; q < 4; ++q) {                                                 \
            float r    = sig2n(ar[q]);                                                \
            float z    = sig2n(az[q]);                                                \
            float n    = tanh2(axn[q] + r * anh[q]);                                  \
            float hnew = n + z * (hreg[q] - n);                                       \
            hreg[q] = upd_ ? hnew : hreg[q];                                          \
        }                                                                             \
        { /* ONE b64 h-write: 4 contiguous halves at [lrow][cb] */                    \
            h4 hv;                                                                    \
            hv[0] = (_Float16)hreg[0]; hv[1] = (_Float16)hreg[1];                     \
            hv[2] = (_Float16)hreg[2]; hv[3] = (_Float16)hreg[3];                     \
            *(h4*)&h_lds[(P) ^ 1][lrow][cb] = hv;                                     \
        }                                                                             \
        /* write staged x-chunk */                                                    \
        if (do_stage) {                                                               \
            const int ws_ = ((t_ >> 3) + 1) & 1;                                      \
            h4 hv;                                                                    \
            hv[0] = (_Float16)xv0[0]; hv[1] = (_Float16)xv0[1];                       \
            hv[2] = (_Float16)xv0[2]; hv[3] = (_Float16)xv0[3];                       \
            *(h4*)&x_lds[ws_][si0][srow][icol] = hv;                                  \
            hv[0] = (_Float16)xv1[0]; hv[1] = (_Float16)xv1[1];                       \
            hv[2] = (_Float16)xv1[2]; hv[3] = (_Float16)xv1[3];                       \
            *(h4*)&x_lds[ws_][si0 + 2][srow][icol] = hv;                              \
            hv[0] = (_Float16)xv2[0]; hv[1] = (_Float16)xv2[1];                       \
            hv[2] = (_Float16)xv2[2]; hv[3] = (_Float16)xv2[3];                       \
            *(h4*)&x_lds[ws_][si0 + 4][srow][icol] = hv;                              \
            hv[0] = (_Float16)xv3[0]; hv[1] = (_Float16)xv3[1];                       \
            hv[2] = (_Float16)xv3[2]; hv[3] = (_Float16)xv3[3];                       \
            *(h4*)&x_lds[ws_][si0 + 6][srow][icol] = hv;                              \
        }                                                                             \
        __syncthreads();                                                              \
    } while (0)

    int t = 0;
    for (; t + 1 < Lmax; t += 2) {
        STEP(0, t);
        STEP(1, t + 1);
    }
    if (t < Lmax) STEP(0, t);

#undef STEP

    // ---- store h (== hn via frozen-h): one dwordx4 per lane ----
    if (gb < B) {
        f4 o;
        o[0] = hreg[0]; o[1] = hreg[1]; o[2] = hreg[2]; o[3] = hreg[3];
        *(f4*)(out + (size_t)gb * H_DIM + cb) = o;
    }
}

extern "C" void kernel_launch(void* const* d_in, const int* in_sizes, int n_in,
                              void* d_out, int out_size, void* d_ws, size_t ws_size,
                              hipStream_t stream) {
    const float* input = (const float*)d_in[0];
    const int*   seq   = (const int*)d_in[1];
    const float* W_ih  = (const float*)d_in[2];
    const float* W_hh  = (const float*)d_in[3];
    const float* b_ih  = (const float*)d_in[4];
    const float* b_hh  = (const float*)d_in[5];
    float* out = (float*)d_out;

    const int B = in_sizes[1];
    const int T = in_sizes[0] / (B * I_DIM);

    const int grid = (B + 15) / 16;
    gru_seq_kernel<<<grid, 512, 0, stream>>>(input, seq, W_ih, W_hh, b_ih, b_hh, out, B, T);
}